// Round 4
// baseline (19.636 us; speedup 1.0000x reference)
//
#include <hip/hip_runtime.h>

#define NBATCH 16
#define NT     50
#define GDIM   128
#define NC     11
#define PLANE  (GDIM * GDIM)        // 16384
#define CONF_BLOCKS 192             // 4 blocks per conf plane, 48 planes
#define TGT_BLOCKS  16              // 1 block per batch
#define TOTAL_BLOCKS (1 + CONF_BLOCKS + TGT_BLOCKS)
#define TPB 256
#define NCONF_PART (CONF_BLOCKS * 4)           // per-wave partials = 768
#define NFLAGS (NCONF_PART + TGT_BLOCKS)       // 784
#define MAGIC64 0x7FF8A55A5AA5F00DULL          // NaN-pattern sentinel; != 0xAA poison

__device__ __forceinline__ float sigm(float x) { return 1.0f / (1.0f + expf(-x)); }

struct TInfo {
    int gi, gj, cls, selm;
    float gx, gy, gw, gh;
};

// valid = tgt.sum()!=0; wh-IoU vs scaled anchors; sel = (any(>0.3) ? >0.3 : argmax) & valid
__device__ __forceinline__ TInfo tinfo(const float* tg) {
    TInfo r;
    float c0 = tg[0], cx = tg[1], cy = tg[2], cw = tg[3], ch = tg[4];
    bool valid = ((c0 + cx + cy + cw + ch) != 0.0f);
    r.gx = cx * (float)GDIM;  r.gy = cy * (float)GDIM;
    r.gw = cw * (float)GDIM;  r.gh = ch * (float)GDIM;
    r.gi = (int)r.gx;  r.gj = (int)r.gy;
    r.cls = (int)c0;
    const float aw[3] = {14.5f, 19.5f, 46.625f};   // ANCHORS / stride(=8)
    const float ah[3] = {11.25f, 24.75f, 40.75f};
    int selm = 0; float best = -1.0f; int bi = 0;
    #pragma unroll
    for (int a = 0; a < 3; a++) {
        float inter = fminf(r.gw, aw[a]) * fminf(r.gh, ah[a]);
        float uni   = r.gw * r.gh + aw[a] * ah[a] - inter;
        float iou   = inter / (uni + 1e-16f);
        if (iou > 0.3f) selm |= (1 << a);
        if (iou > best) { best = iou; bi = a; }
    }
    if (selm == 0) selm = (1 << bi);
    if (!valid) selm = 0;
    r.selm = selm;
    return r;
}

// ws floats: [0..768) conf wave-partials | [768..912) tgt sums (16x9) |
// float offset 912 (byte 3648, 8B-aligned): u64 flags[784]
__global__ __launch_bounds__(TPB) void k_fused(const float* __restrict__ X,
                                               const float* __restrict__ T,
                                               float* __restrict__ ws,
                                               float* __restrict__ out) {
    const int bid = blockIdx.x, tid = threadIdx.x;
    float* partials = ws;                          // 768
    float* tsums    = ws + NCONF_PART;             // 144
    unsigned long long* flags = (unsigned long long*)(ws + 912);

    if (bid == 0) {
        // ---- finalizer: poll worker flags, then fixed-order reduce ----
        __shared__ float sred[4];
        __shared__ float st[TGT_BLOCKS * 9];
        for (int i = tid; i < NFLAGS; i += TPB) {
            while (__hip_atomic_load(&flags[i], __ATOMIC_ACQUIRE,
                                     __HIP_MEMORY_SCOPE_AGENT) != MAGIC64)
                __builtin_amdgcn_s_sleep(1);
        }
        __syncthreads();
        float v = 0.0f;
        for (int i = tid; i < NCONF_PART; i += TPB)
            v += __hip_atomic_load(&partials[i], __ATOMIC_RELAXED, __HIP_MEMORY_SCOPE_AGENT);
        #pragma unroll
        for (int o = 32; o > 0; o >>= 1) v += __shfl_down(v, o);
        if ((tid & 63) == 0) sred[tid >> 6] = v;
        if (tid < TGT_BLOCKS * 9)
            st[tid] = __hip_atomic_load(&tsums[tid], __ATOMIC_RELAXED, __HIP_MEMORY_SCOPE_AGENT);
        __syncthreads();
        if (tid == 0) {
            float f[9] = {0, 0, 0, 0, 0, 0, 0, 0, 0};
            f[5] = sred[0] + sred[1] + sred[2] + sred[3];
            #pragma unroll
            for (int b = 0; b < TGT_BLOCKS; b++)
                #pragma unroll
                for (int c = 0; c < 9; c++) f[c] += st[b * 9 + c];
            float total = f[0] + f[1] + f[2] + f[3] + f[4] + f[6] + f[5];
            out[0] = total;
            out[1] = f[0]; out[2] = f[1]; out[3] = f[2]; out[4] = f[3];
            out[5] = f[4]; out[6] = f[5]; out[7] = f[6];
            float nGT = f[7], nCorr = f[8];
            out[8] = (nGT > 0.0f) ? (nCorr / fmaxf(nGT, 1.0f)) : 1.0f;
        }
        return;
    }

    if (bid <= CONF_BLOCKS) {
        // ---- dense 0.5*sum(sigmoid(conf)^2); 4 blocks per plane, no barriers ----
        const float4* X4 = reinterpret_cast<const float4*>(X);
        int cb = bid - 1;
        int p = cb >> 2, q = cb & 3;       // plane 0..47, quarter
        int bb = p / 3, a = p - bb * 3;    // one div per thread total
        int base4 = (bb * 48 + a * 16 + 4) * 4096 + q * 1024;
        float s = 0.0f;
        #pragma unroll
        for (int k = 0; k < 4; k++) {
            float4 v = X4[base4 + k * 256 + tid];
            float c0 = sigm(v.x), c1 = sigm(v.y), c2 = sigm(v.z), c3 = sigm(v.w);
            s += c0 * c0 + c1 * c1 + c2 * c2 + c3 * c3;
        }
        #pragma unroll
        for (int o = 32; o > 0; o >>= 1) s += __shfl_down(s, o);
        if ((tid & 63) == 0) {
            int w = cb * 4 + (tid >> 6);
            partials[w] = 0.5f * s;
            __hip_atomic_store(&flags[w], MAGIC64, __ATOMIC_RELEASE,
                               __HIP_MEMORY_SCOPE_AGENT);
        }
        return;
    }

    // ---- target block: one batch (50 targets), wave 0 computes ----
    __shared__ float stg[NT * 5];
    __shared__ int   pk[NT];
    int b = bid - 1 - CONF_BLOCKS;
    for (int i = tid; i < NT * 5; i += TPB) stg[i] = T[b * NT * 5 + i];
    __syncthreads();
    TInfo me; me.selm = 0;
    if (tid < NT) {
        me = tinfo(stg + tid * 5);
        pk[tid] = me.gi | (me.gj << 7) | (me.selm << 14) | (me.cls << 17);
    }
    __syncthreads();
    if (tid >= 64) return;    // waves 1..3 done (helped stage only)

    float res[9] = {0, 0, 0, 0, 0, 0, 0, 0, 0};
    // res: 0..3 lx,ly,lw,lh  4 lconf  5 lconf_no(corr)  6 lcls  7 nGT  8 nCorrect
    if (me.selm) {
        int mykey = pk[tid] & 0x3FFF;
        int latmask = 0;
        int clsb[3] = {0, 0, 0};
        for (int e = 0; e < NT; e++) {
            int o = pk[e];
            int os = (o >> 14) & 7;
            if (os && ((o & 0x3FFF) == mykey)) {
                int cb2 = 1 << ((o >> 17) & 0xF);
                if (os & 1) clsb[0] |= cb2;
                if (os & 2) clsb[1] |= cb2;
                if (os & 4) clsb[2] |= cb2;
                if (e > tid) latmask |= os;
            }
        }

        const float aw[3] = {14.5f, 19.5f, 46.625f};
        const float ah[3] = {11.25f, 24.75f, 40.75f};
        float g_x1 = me.gx - me.gw * 0.5f, g_x2 = me.gx + me.gw * 0.5f;
        float g_y1 = me.gy - me.gh * 0.5f, g_y2 = me.gy + me.gh * 0.5f;
        bool anyv = false;

        #pragma unroll
        for (int a = 0; a < 3; a++) {
            if (!((me.selm >> a) & 1)) continue;
            int base = (b * 48 + a * 16) * PLANE + me.gj * GDIM + me.gi;
            float x0 = X[base];
            float x1 = X[base + PLANE];
            float x2 = X[base + 2 * PLANE];
            float x3 = X[base + 3 * PLANE];
            float bx = sigm(x0) + (float)me.gi;
            float by = sigm(x1) + (float)me.gj;
            float bw = expf(x2) * aw[a];
            float bh = expf(x3) * ah[a];
            float iw = fmaxf(fminf(g_x2, bx + bw * 0.5f) - fmaxf(g_x1, bx - bw * 0.5f), 0.0f);
            float ih = fmaxf(fminf(g_y2, by + bh * 0.5f) - fmaxf(g_y1, by - bh * 0.5f), 0.0f);
            float inter = iw * ih;
            float iou = inter / (me.gw * me.gh + bw * bh - inter + 1e-16f);
            if (iou > 0.5f) anyv = true;

            if (!((latmask >> a) & 1)) {   // unique last-writer for this cell-anchor
                float conf = sigm(X[base + 4 * PLANE]);
                float px = sigm(x0), py = sigm(x1);
                float txv = me.gx - (float)me.gi;
                float tyv = me.gy - (float)me.gj;
                float twv = logf(me.gw / aw[a] + 1e-16f);
                float thv = logf(me.gh / ah[a] + 1e-16f);
                res[0] += 100.0f * (px - txv) * (px - txv);
                res[1] += 100.0f * (py - tyv) * (py - tyv);
                res[2] += 100.0f * (x2 - twv) * (x2 - twv);
                res[3] += 100.0f * (x3 - thv) * (x3 - thv);
                res[4] += (conf - 1.0f) * (conf - 1.0f);
                res[5] -= 0.5f * conf * conf;   // cancel dense no-obj term
                float l[NC]; float mx = -1e30f;
                #pragma unroll
                for (int c = 0; c < NC; c++) {
                    l[c] = X[base + (5 + c) * PLANE];
                    mx = fmaxf(mx, l[c]);
                }
                float S = 0.0f;
                #pragma unroll
                for (int c = 0; c < NC; c++) { l[c] = expf(l[c] - mx); S += l[c]; }
                float invS = 1.0f / S;
                #pragma unroll
                for (int c = 0; c < NC; c++) {
                    float p = l[c] * invS;
                    float term = ((clsb[a] >> c) & 1) ? fmaxf(logf(p), -100.0f)
                                                      : fmaxf(logf(1.0f - p), -100.0f);
                    res[6] -= term;
                }
            }
        }
        res[7] = 1.0f;
        res[8] = anyv ? 1.0f : 0.0f;
    }

    #pragma unroll
    for (int o = 32; o > 0; o >>= 1) {
        #pragma unroll
        for (int c = 0; c < 9; c++) res[c] += __shfl_down(res[c], o);
    }
    if (tid == 0) {
        #pragma unroll
        for (int c = 0; c < 9; c++) tsums[b * 9 + c] = res[c];
        __hip_atomic_store(&flags[NCONF_PART + b], MAGIC64, __ATOMIC_RELEASE,
                           __HIP_MEMORY_SCOPE_AGENT);
    }
}

extern "C" void kernel_launch(void* const* d_in, const int* in_sizes, int n_in,
                              void* d_out, int out_size, void* d_ws, size_t ws_size,
                              hipStream_t stream) {
    const float* X = (const float*)d_in[0];   // (16,48,128,128) f32
    const float* T = (const float*)d_in[1];   // (16,50,5) f32
    float* out = (float*)d_out;               // 9 f32 scalars
    float* wsf = (float*)d_ws;

    k_fused<<<TOTAL_BLOCKS, TPB, 0, stream>>>(X, T, wsf, out);
}

// Round 5
// 17.997 us; speedup vs baseline: 1.0911x; 1.0911x over previous
//
#include <hip/hip_runtime.h>

#define NBATCH 16
#define NT     50
#define GDIM   128
#define NC     11
#define PLANE  (GDIM * GDIM)        // 16384
#define CONF_BLOCKS 192             // 4 blocks per conf plane, 48 planes
#define TGT_BLOCKS  4               // 4 blocks x 200 targets (4 batches each)
#define TOTAL_BLOCKS (1 + CONF_BLOCKS + TGT_BLOCKS)
#define TPB 256
#define NSLOTS (CONF_BLOCKS + TGT_BLOCKS * 9)   // 192 conf + 36 tgt = 228
#define MAGIC32 0x7FC0DEADu                      // NaN-pattern tag; != 0xAAAAAAAA poison

__device__ __forceinline__ float sigm(float x) { return 1.0f / (1.0f + expf(-x)); }

__device__ __forceinline__ void put_slot(unsigned long long* slot, float v) {
    unsigned long long pk = ((unsigned long long)MAGIC32 << 32) |
                            (unsigned long long)__float_as_uint(v);
    __hip_atomic_store(slot, pk, __ATOMIC_RELAXED, __HIP_MEMORY_SCOPE_AGENT);
}

struct TInfo {
    int gi, gj, cls, selm;
    float gx, gy, gw, gh;
};

// valid = tgt.sum()!=0; wh-IoU vs scaled anchors; sel = (any(>0.3) ? >0.3 : argmax) & valid
__device__ __forceinline__ TInfo tinfo(const float* tg) {
    TInfo r;
    float c0 = tg[0], cx = tg[1], cy = tg[2], cw = tg[3], ch = tg[4];
    bool valid = ((c0 + cx + cy + cw + ch) != 0.0f);
    r.gx = cx * (float)GDIM;  r.gy = cy * (float)GDIM;
    r.gw = cw * (float)GDIM;  r.gh = ch * (float)GDIM;
    r.gi = (int)r.gx;  r.gj = (int)r.gy;
    r.cls = (int)c0;
    const float aw[3] = {14.5f, 19.5f, 46.625f};   // ANCHORS / stride(=8)
    const float ah[3] = {11.25f, 24.75f, 40.75f};
    int selm = 0; float best = -1.0f; int bi = 0;
    #pragma unroll
    for (int a = 0; a < 3; a++) {
        float inter = fminf(r.gw, aw[a]) * fminf(r.gh, ah[a]);
        float uni   = r.gw * r.gh + aw[a] * ah[a] - inter;
        float iou   = inter / (uni + 1e-16f);
        if (iou > 0.3f) selm |= (1 << a);
        if (iou > best) { best = iou; bi = a; }
    }
    if (selm == 0) selm = (1 << bi);
    if (!valid) selm = 0;
    r.selm = selm;
    return r;
}

// ws: u64 slots[228]. slot[0..191]=conf block partials, slot[192+tb*9+c]=tgt sums.
// Each slot is {MAGIC32, float_bits} — value rides with flag, no fences needed.
__global__ __launch_bounds__(TPB) void k_fused(const float* __restrict__ X,
                                               const float* __restrict__ T,
                                               float* __restrict__ ws,
                                               float* __restrict__ out) {
    const int bid = blockIdx.x, tid = threadIdx.x;
    unsigned long long* slots = (unsigned long long*)ws;
    __shared__ float sred[4][9];

    if (bid == 0) {
        // ---- finalizer: poll self-tagged slots (relaxed), fixed-order reduce ----
        __shared__ float st[TGT_BLOCKS * 9];
        float myval = 0.0f;
        if (tid < NSLOTS) {
            unsigned long long v;
            for (;;) {
                v = __hip_atomic_load(&slots[tid], __ATOMIC_RELAXED,
                                      __HIP_MEMORY_SCOPE_AGENT);
                if ((unsigned)(v >> 32) == MAGIC32) break;
                __builtin_amdgcn_s_sleep(1);
            }
            myval = __uint_as_float((unsigned)v);
            if (tid >= CONF_BLOCKS) st[tid - CONF_BLOCKS] = myval;
        }
        __syncthreads();
        float cv = (tid < CONF_BLOCKS) ? myval : 0.0f;
        #pragma unroll
        for (int o = 32; o > 0; o >>= 1) cv += __shfl_down(cv, o);
        if ((tid & 63) == 0) sred[tid >> 6][0] = cv;
        __syncthreads();
        if (tid == 0) {
            float f[9] = {0, 0, 0, 0, 0, 0, 0, 0, 0};
            f[5] = sred[0][0] + sred[1][0] + sred[2][0] + sred[3][0];
            #pragma unroll
            for (int b = 0; b < TGT_BLOCKS; b++)
                #pragma unroll
                for (int c = 0; c < 9; c++) f[c] += st[b * 9 + c];
            float total = f[0] + f[1] + f[2] + f[3] + f[4] + f[6] + f[5];
            out[0] = total;
            out[1] = f[0]; out[2] = f[1]; out[3] = f[2]; out[4] = f[3];
            out[5] = f[4]; out[6] = f[5]; out[7] = f[6];
            float nGT = f[7], nCorr = f[8];
            out[8] = (nGT > 0.0f) ? (nCorr / fmaxf(nGT, 1.0f)) : 1.0f;
        }
        return;
    }

    if (bid <= CONF_BLOCKS) {
        // ---- dense 0.5*sum(sigmoid(conf)^2); 4 blocks per plane ----
        const float4* X4 = reinterpret_cast<const float4*>(X);
        int cb = bid - 1;
        int p = cb >> 2, q = cb & 3;       // plane 0..47, quarter
        int bb = p / 3, a = p - bb * 3;
        int base4 = (bb * 48 + a * 16 + 4) * 4096 + q * 1024;
        float s = 0.0f;
        #pragma unroll
        for (int k = 0; k < 4; k++) {
            float4 v = X4[base4 + k * 256 + tid];
            float c0 = sigm(v.x), c1 = sigm(v.y), c2 = sigm(v.z), c3 = sigm(v.w);
            s += c0 * c0 + c1 * c1 + c2 * c2 + c3 * c3;
        }
        #pragma unroll
        for (int o = 32; o > 0; o >>= 1) s += __shfl_down(s, o);
        if ((tid & 63) == 0) sred[tid >> 6][0] = s;
        __syncthreads();
        if (tid == 0)
            put_slot(&slots[cb], 0.5f * (sred[0][0] + sred[1][0] + sred[2][0] + sred[3][0]));
        return;
    }

    // ---- target block: 200 targets (4 batches) ----
    __shared__ float stg[200 * 5];
    __shared__ int   pk[200];
    int tb = bid - 1 - CONF_BLOCKS;
    float res[9] = {0, 0, 0, 0, 0, 0, 0, 0, 0};
    // res: 0..3 lx,ly,lw,lh  4 lconf  5 lconf_no(corr)  6 lcls  7 nGT  8 nCorrect
    for (int i = tid; i < 1000; i += TPB) stg[i] = T[tb * 1000 + i];
    __syncthreads();
    TInfo me; me.selm = 0;
    if (tid < 200) {
        me = tinfo(stg + tid * 5);
        pk[tid] = me.gi | (me.gj << 7) | (me.selm << 14) | (me.cls << 17);
    }
    __syncthreads();
    if (me.selm) {
        int lb = tid / 50, lk = tid % 50;
        int b = tb * 4 + lb;
        const int* pb = pk + lb * 50;
        int mykey = pk[tid] & 0x3FFF;
        int latmask = 0;
        int clsb[3] = {0, 0, 0};
        for (int e = 0; e < 50; e++) {
            int o = pb[e];
            int os = (o >> 14) & 7;
            if (os && ((o & 0x3FFF) == mykey)) {
                int cb2 = 1 << ((o >> 17) & 0xF);
                if (os & 1) clsb[0] |= cb2;
                if (os & 2) clsb[1] |= cb2;
                if (os & 4) clsb[2] |= cb2;
                if (e > lk) latmask |= os;
            }
        }

        const float aw[3] = {14.5f, 19.5f, 46.625f};
        const float ah[3] = {11.25f, 24.75f, 40.75f};
        float g_x1 = me.gx - me.gw * 0.5f, g_x2 = me.gx + me.gw * 0.5f;
        float g_y1 = me.gy - me.gh * 0.5f, g_y2 = me.gy + me.gh * 0.5f;
        bool anyv = false;

        #pragma unroll
        for (int a = 0; a < 3; a++) {
            if (!((me.selm >> a) & 1)) continue;
            int base = (b * 48 + a * 16) * PLANE + me.gj * GDIM + me.gi;
            float x0 = X[base];
            float x1 = X[base + PLANE];
            float x2 = X[base + 2 * PLANE];
            float x3 = X[base + 3 * PLANE];
            float bx = sigm(x0) + (float)me.gi;
            float by = sigm(x1) + (float)me.gj;
            float bw = expf(x2) * aw[a];
            float bh = expf(x3) * ah[a];
            float iw = fmaxf(fminf(g_x2, bx + bw * 0.5f) - fmaxf(g_x1, bx - bw * 0.5f), 0.0f);
            float ih = fmaxf(fminf(g_y2, by + bh * 0.5f) - fmaxf(g_y1, by - bh * 0.5f), 0.0f);
            float inter = iw * ih;
            float iou = inter / (me.gw * me.gh + bw * bh - inter + 1e-16f);
            if (iou > 0.5f) anyv = true;

            if (!((latmask >> a) & 1)) {   // unique last-writer for this cell-anchor
                float conf = sigm(X[base + 4 * PLANE]);
                float px = sigm(x0), py = sigm(x1);
                float txv = me.gx - (float)me.gi;
                float tyv = me.gy - (float)me.gj;
                float twv = logf(me.gw / aw[a] + 1e-16f);
                float thv = logf(me.gh / ah[a] + 1e-16f);
                res[0] += 100.0f * (px - txv) * (px - txv);
                res[1] += 100.0f * (py - tyv) * (py - tyv);
                res[2] += 100.0f * (x2 - twv) * (x2 - twv);
                res[3] += 100.0f * (x3 - thv) * (x3 - thv);
                res[4] += (conf - 1.0f) * (conf - 1.0f);
                res[5] -= 0.5f * conf * conf;   // cancel dense no-obj term
                float l[NC]; float mx = -1e30f;
                #pragma unroll
                for (int c = 0; c < NC; c++) {
                    l[c] = X[base + (5 + c) * PLANE];
                    mx = fmaxf(mx, l[c]);
                }
                float S = 0.0f;
                #pragma unroll
                for (int c = 0; c < NC; c++) { l[c] = expf(l[c] - mx); S += l[c]; }
                float invS = 1.0f / S;
                #pragma unroll
                for (int c = 0; c < NC; c++) {
                    float p = l[c] * invS;
                    float term = ((clsb[a] >> c) & 1) ? fmaxf(logf(p), -100.0f)
                                                      : fmaxf(logf(1.0f - p), -100.0f);
                    res[6] -= term;
                }
            }
        }
        res[7] = 1.0f;
        res[8] = anyv ? 1.0f : 0.0f;
    }

    #pragma unroll
    for (int o = 32; o > 0; o >>= 1) {
        #pragma unroll
        for (int c = 0; c < 9; c++) res[c] += __shfl_down(res[c], o);
    }
    if ((tid & 63) == 0) {
        #pragma unroll
        for (int c = 0; c < 9; c++) sred[tid >> 6][c] = res[c];
    }
    __syncthreads();
    if (tid == 0) {
        #pragma unroll
        for (int c = 0; c < 9; c++)
            put_slot(&slots[CONF_BLOCKS + tb * 9 + c],
                     sred[0][c] + sred[1][c] + sred[2][c] + sred[3][c]);
    }
}

extern "C" void kernel_launch(void* const* d_in, const int* in_sizes, int n_in,
                              void* d_out, int out_size, void* d_ws, size_t ws_size,
                              hipStream_t stream) {
    const float* X = (const float*)d_in[0];   // (16,48,128,128) f32
    const float* T = (const float*)d_in[1];   // (16,50,5) f32
    float* out = (float*)d_out;               // 9 f32 scalars
    float* wsf = (float*)d_ws;

    k_fused<<<TOTAL_BLOCKS, TPB, 0, stream>>>(X, T, wsf, out);
}

// Round 6
// 11.633 us; speedup vs baseline: 1.6880x; 1.5471x over previous
//
#include <hip/hip_runtime.h>

#define NBATCH 16
#define NT     50
#define GDIM   128
#define NC     11
#define PLANE  (GDIM * GDIM)        // 16384
#define CONF_BLOCKS 192             // 4 blocks per conf plane, 48 planes
#define TGT_BLOCKS  16              // 1 block per batch, thread=(target,anchor)
#define TOTAL_BLOCKS (1 + CONF_BLOCKS + TGT_BLOCKS)
#define TPB 256
#define NSLOTS (CONF_BLOCKS + TGT_BLOCKS * 9)   // 192 + 144 = 336
#define MAGIC32 0x7FC0DEADu                      // NaN-pattern tag; != 0xAAAAAAAA poison

__device__ __forceinline__ float sigm(float x) { return 1.0f / (1.0f + expf(-x)); }

__device__ __forceinline__ void put_slot(unsigned long long* slot, float v) {
    unsigned long long pk = ((unsigned long long)MAGIC32 << 32) |
                            (unsigned long long)__float_as_uint(v);
    __hip_atomic_store(slot, pk, __ATOMIC_RELAXED, __HIP_MEMORY_SCOPE_AGENT);
}

struct TInfo {
    int gi, gj, cls, selm;
    float gx, gy, gw, gh;
};

// valid = tgt.sum()!=0; wh-IoU vs scaled anchors; sel = (any(>0.3) ? >0.3 : argmax) & valid
__device__ __forceinline__ TInfo tinfo(const float* tg) {
    TInfo r;
    float c0 = tg[0], cx = tg[1], cy = tg[2], cw = tg[3], ch = tg[4];
    bool valid = ((c0 + cx + cy + cw + ch) != 0.0f);
    r.gx = cx * (float)GDIM;  r.gy = cy * (float)GDIM;
    r.gw = cw * (float)GDIM;  r.gh = ch * (float)GDIM;
    r.gi = (int)r.gx;  r.gj = (int)r.gy;
    r.cls = (int)c0;
    const float aw[3] = {14.5f, 19.5f, 46.625f};   // ANCHORS / stride(=8)
    const float ah[3] = {11.25f, 24.75f, 40.75f};
    int selm = 0; float best = -1.0f; int bi = 0;
    #pragma unroll
    for (int a = 0; a < 3; a++) {
        float inter = fminf(r.gw, aw[a]) * fminf(r.gh, ah[a]);
        float uni   = r.gw * r.gh + aw[a] * ah[a] - inter;
        float iou   = inter / (uni + 1e-16f);
        if (iou > 0.3f) selm |= (1 << a);
        if (iou > best) { best = iou; bi = a; }
    }
    if (selm == 0) selm = (1 << bi);
    if (!valid) selm = 0;
    r.selm = selm;
    return r;
}

// ws: u64 slots[336]. slot[0..191]=conf partials, slot[192+b*9+c]=tgt sums.
// Each slot = {MAGIC32, float_bits} — value rides with tag, no fences needed.
__global__ __launch_bounds__(TPB) void k_fused(const float* __restrict__ X,
                                               const float* __restrict__ T,
                                               float* __restrict__ ws,
                                               float* __restrict__ out) {
    const int bid = blockIdx.x, tid = threadIdx.x;
    unsigned long long* slots = (unsigned long long*)ws;

    if (bid == 0) {
        // ---- finalizer: poll self-tagged slots (relaxed), fixed-order reduce ----
        __shared__ float st[TGT_BLOCKS * 9];
        __shared__ float sf[9];
        __shared__ float sredc[4];
        float cv = 0.0f;
        for (int i = tid; i < NSLOTS; i += TPB) {
            unsigned long long v;
            for (;;) {
                v = __hip_atomic_load(&slots[i], __ATOMIC_RELAXED,
                                      __HIP_MEMORY_SCOPE_AGENT);
                if ((unsigned)(v >> 32) == MAGIC32) break;
                __builtin_amdgcn_s_sleep(1);
            }
            float val = __uint_as_float((unsigned)v);
            if (i < CONF_BLOCKS) cv += val;
            else st[i - CONF_BLOCKS] = val;
        }
        __syncthreads();
        #pragma unroll
        for (int o = 32; o > 0; o >>= 1) cv += __shfl_down(cv, o);
        if ((tid & 63) == 0) sredc[tid >> 6] = cv;
        if (tid < 9) {
            float fc = 0.0f;
            #pragma unroll
            for (int b = 0; b < TGT_BLOCKS; b++) fc += st[b * 9 + tid];
            sf[tid] = fc;
        }
        __syncthreads();
        if (tid == 0) {
            float f[9];
            #pragma unroll
            for (int c = 0; c < 9; c++) f[c] = sf[c];
            f[5] += sredc[0] + sredc[1] + sredc[2] + sredc[3];
            float total = f[0] + f[1] + f[2] + f[3] + f[4] + f[6] + f[5];
            out[0] = total;
            out[1] = f[0]; out[2] = f[1]; out[3] = f[2]; out[4] = f[3];
            out[5] = f[4]; out[6] = f[5]; out[7] = f[6];
            float nGT = f[7], nCorr = f[8];
            out[8] = (nGT > 0.0f) ? (nCorr / fmaxf(nGT, 1.0f)) : 1.0f;
        }
        return;
    }

    if (bid <= CONF_BLOCKS) {
        // ---- dense 0.5*sum(sigmoid(conf)^2); 4 blocks per plane ----
        __shared__ float sred[4];
        const float4* X4 = reinterpret_cast<const float4*>(X);
        int cb = bid - 1;
        int p = cb >> 2, q = cb & 3;       // plane 0..47, quarter
        int bb = p / 3, a = p - bb * 3;
        int base4 = (bb * 48 + a * 16 + 4) * 4096 + q * 1024;
        float s = 0.0f;
        #pragma unroll
        for (int k = 0; k < 4; k++) {
            float4 v = X4[base4 + k * 256 + tid];
            float c0 = sigm(v.x), c1 = sigm(v.y), c2 = sigm(v.z), c3 = sigm(v.w);
            s += c0 * c0 + c1 * c1 + c2 * c2 + c3 * c3;
        }
        #pragma unroll
        for (int o = 32; o > 0; o >>= 1) s += __shfl_down(s, o);
        if ((tid & 63) == 0) sred[tid >> 6] = s;
        __syncthreads();
        if (tid == 0)
            put_slot(&slots[cb], 0.5f * (sred[0] + sred[1] + sred[2] + sred[3]));
        return;
    }

    // ---- target block: one batch, thread = (target t, anchor a), tid = t*3+a ----
    __shared__ float stg[NT * 5];
    __shared__ int   pk[NT];
    __shared__ int   sanyv[NT * 3];
    __shared__ float sred[4][9];
    int b = bid - 1 - CONF_BLOCKS;
    for (int i = tid; i < NT * 5; i += TPB) stg[i] = T[b * NT * 5 + i];
    __syncthreads();

    TInfo me; me.selm = 0;
    int t = 0, a = 0;
    if (tid < NT * 3) {
        t = tid / 3; a = tid - t * 3;
        me = tinfo(stg + t * 5);
        if (a == 0) pk[t] = me.gi | (me.gj << 7) | (me.selm << 14) | (me.cls << 17);
    }
    __syncthreads();

    float res[9] = {0, 0, 0, 0, 0, 0, 0, 0, 0};
    // res: 0..3 lx,ly,lw,lh  4 lconf  5 lconf_no(corr)  6 lcls  7 nGT  8 nCorrect
    int anyv = 0;
    bool selA = (tid < NT * 3) && ((me.selm >> a) & 1);
    if (selA) {
        int mykey = me.gi | (me.gj << 7);
        int lat = 0, clsba = 0;
        for (int e = 0; e < NT; e++) {
            int o = pk[e];
            if (((o >> (14 + a)) & 1) && ((o & 0x3FFF) == mykey)) {
                clsba |= 1 << ((o >> 17) & 0xF);
                if (e > t) lat = 1;
            }
        }
        float awa = (a == 0) ? 14.5f  : (a == 1) ? 19.5f  : 46.625f;
        float aha = (a == 0) ? 11.25f : (a == 1) ? 24.75f : 40.75f;
        int base = (b * 48 + a * 16) * PLANE + me.gj * GDIM + me.gi;
        float x0 = X[base];
        float x1 = X[base + PLANE];
        float x2 = X[base + 2 * PLANE];
        float x3 = X[base + 3 * PLANE];
        // nCorrect: center IoU of pred box vs gt at this cell-anchor
        float g_x1 = me.gx - me.gw * 0.5f, g_x2 = me.gx + me.gw * 0.5f;
        float g_y1 = me.gy - me.gh * 0.5f, g_y2 = me.gy + me.gh * 0.5f;
        float bx = sigm(x0) + (float)me.gi;
        float by = sigm(x1) + (float)me.gj;
        float bw = expf(x2) * awa;
        float bh = expf(x3) * aha;
        float iw = fmaxf(fminf(g_x2, bx + bw * 0.5f) - fmaxf(g_x1, bx - bw * 0.5f), 0.0f);
        float ih = fmaxf(fminf(g_y2, by + bh * 0.5f) - fmaxf(g_y1, by - bh * 0.5f), 0.0f);
        float inter = iw * ih;
        float iou = inter / (me.gw * me.gh + bw * bh - inter + 1e-16f);
        anyv = (iou > 0.5f) ? 1 : 0;

        if (!lat) {   // unique last-writer for this cell-anchor
            float conf = sigm(X[base + 4 * PLANE]);
            float px = sigm(x0), py = sigm(x1);
            float txv = me.gx - (float)me.gi;
            float tyv = me.gy - (float)me.gj;
            float twv = logf(me.gw / awa + 1e-16f);
            float thv = logf(me.gh / aha + 1e-16f);
            res[0] = 100.0f * (px - txv) * (px - txv);
            res[1] = 100.0f * (py - tyv) * (py - tyv);
            res[2] = 100.0f * (x2 - twv) * (x2 - twv);
            res[3] = 100.0f * (x3 - thv) * (x3 - thv);
            res[4] = (conf - 1.0f) * (conf - 1.0f);
            res[5] = -0.5f * conf * conf;   // cancel dense no-obj term
            float l[NC]; float mx = -1e30f;
            #pragma unroll
            for (int c = 0; c < NC; c++) {
                l[c] = X[base + (5 + c) * PLANE];
                mx = fmaxf(mx, l[c]);
            }
            float S = 0.0f;
            #pragma unroll
            for (int c = 0; c < NC; c++) { l[c] = expf(l[c] - mx); S += l[c]; }
            float invS = 1.0f / S;
            float lcls = 0.0f;
            #pragma unroll
            for (int c = 0; c < NC; c++) {
                float p = l[c] * invS;
                float term = ((clsba >> c) & 1) ? fmaxf(logf(p), -100.0f)
                                                : fmaxf(logf(1.0f - p), -100.0f);
                lcls -= term;
            }
            res[6] = lcls;
        }
    }
    if (tid < NT * 3) sanyv[tid] = anyv;
    if (tid < NT * 3 && a == 0 && me.selm) res[7] = 1.0f;   // nGT (valid <=> selm!=0)
    __syncthreads();
    if (tid < NT * 3 && a == 0 && me.selm)
        res[8] = (sanyv[tid] | sanyv[tid + 1] | sanyv[tid + 2]) ? 1.0f : 0.0f;

    #pragma unroll
    for (int o = 32; o > 0; o >>= 1) {
        #pragma unroll
        for (int c = 0; c < 9; c++) res[c] += __shfl_down(res[c], o);
    }
    if ((tid & 63) == 0) {
        #pragma unroll
        for (int c = 0; c < 9; c++) sred[tid >> 6][c] = res[c];
    }
    __syncthreads();
    if (tid == 0) {
        #pragma unroll
        for (int c = 0; c < 9; c++)
            put_slot(&slots[CONF_BLOCKS + b * 9 + c],
                     sred[0][c] + sred[1][c] + sred[2][c] + sred[3][c]);
    }
}

extern "C" void kernel_launch(void* const* d_in, const int* in_sizes, int n_in,
                              void* d_out, int out_size, void* d_ws, size_t ws_size,
                              hipStream_t stream) {
    const float* X = (const float*)d_in[0];   // (16,48,128,128) f32
    const float* T = (const float*)d_in[1];   // (16,50,5) f32
    float* out = (float*)d_out;               // 9 f32 scalars
    float* wsf = (float*)d_ws;

    k_fused<<<TOTAL_BLOCKS, TPB, 0, stream>>>(X, T, wsf, out);
}

// Round 7
// 11.537 us; speedup vs baseline: 1.7020x; 1.0083x over previous
//
#include <hip/hip_runtime.h>

#define NBATCH 16
#define NT     50
#define GDIM   128
#define NC     11
#define PLANE  (GDIM * GDIM)        // 16384
#define CONF_BLOCKS 192             // 4 blocks per conf plane, 48 planes
#define TGT_BLOCKS  16              // 1 block per batch, thread=(target,anchor)
#define TOTAL_BLOCKS (1 + CONF_BLOCKS + TGT_BLOCKS)
#define TPB 256
#define NCONF_SLOTS (CONF_BLOCKS * 4)            // per-wave: 768
#define NTGT_SLOTS  (TGT_BLOCKS * 4 * 9)         // per-wave x 9ch: 576
#define NSLOTS (NCONF_SLOTS + NTGT_SLOTS)        // 1344
#define MAGIC32 0x7FC0DEADu                      // NaN-pattern tag; != 0xAAAAAAAA poison

__device__ __forceinline__ float sigm(float x) { return 1.0f / (1.0f + expf(-x)); }

__device__ __forceinline__ void put_slot(unsigned long long* slot, float v) {
    unsigned long long pk = ((unsigned long long)MAGIC32 << 32) |
                            (unsigned long long)__float_as_uint(v);
    __hip_atomic_store(slot, pk, __ATOMIC_RELAXED, __HIP_MEMORY_SCOPE_AGENT);
}

__device__ __forceinline__ float poll_slot(const unsigned long long* slot) {
    unsigned long long v;
    for (;;) {
        v = __hip_atomic_load(slot, __ATOMIC_RELAXED, __HIP_MEMORY_SCOPE_AGENT);
        if ((unsigned)(v >> 32) == MAGIC32) break;
        __builtin_amdgcn_s_sleep(1);
    }
    return __uint_as_float((unsigned)v);
}

struct TInfo {
    int gi, gj, cls, selm;
    float gx, gy, gw, gh;
};

// valid = tgt.sum()!=0; wh-IoU vs scaled anchors; sel = (any(>0.3) ? >0.3 : argmax) & valid
__device__ __forceinline__ TInfo tinfo(const float* tg) {
    TInfo r;
    float c0 = tg[0], cx = tg[1], cy = tg[2], cw = tg[3], ch = tg[4];
    bool valid = ((c0 + cx + cy + cw + ch) != 0.0f);
    r.gx = cx * (float)GDIM;  r.gy = cy * (float)GDIM;
    r.gw = cw * (float)GDIM;  r.gh = ch * (float)GDIM;
    r.gi = (int)r.gx;  r.gj = (int)r.gy;
    r.cls = (int)c0;
    const float aw[3] = {14.5f, 19.5f, 46.625f};   // ANCHORS / stride(=8)
    const float ah[3] = {11.25f, 24.75f, 40.75f};
    int selm = 0; float best = -1.0f; int bi = 0;
    #pragma unroll
    for (int a = 0; a < 3; a++) {
        float inter = fminf(r.gw, aw[a]) * fminf(r.gh, ah[a]);
        float uni   = r.gw * r.gh + aw[a] * ah[a] - inter;
        float iou   = inter / (uni + 1e-16f);
        if (iou > 0.3f) selm |= (1 << a);
        if (iou > best) { best = iou; bi = a; }
    }
    if (selm == 0) selm = (1 << bi);
    if (!valid) selm = 0;
    r.selm = selm;
    return r;
}

// ws: u64 slots[1344]. [0..768)=conf per-wave partials (cb*4+w);
// [768..1344)=tgt per-wave sums ((b*4+w)*9+c). Slot = {MAGIC32, float_bits}.
__global__ __launch_bounds__(TPB) void k_fused(const float* __restrict__ X,
                                               const float* __restrict__ T,
                                               float* __restrict__ ws,
                                               float* __restrict__ out) {
    const int bid = blockIdx.x, tid = threadIdx.x;
    unsigned long long* slots = (unsigned long long*)ws;

    if (bid == 0) {
        // ---- finalizer: poll self-tagged slots (relaxed), fixed-order reduce ----
        __shared__ float st[NTGT_SLOTS];
        __shared__ float sf[9];
        __shared__ float sredc[4];
        float cv = 0.0f;
        for (int i = tid; i < NCONF_SLOTS; i += TPB) cv += poll_slot(&slots[i]);
        for (int i = tid; i < NTGT_SLOTS; i += TPB) st[i] = poll_slot(&slots[NCONF_SLOTS + i]);
        __syncthreads();
        #pragma unroll
        for (int o = 32; o > 0; o >>= 1) cv += __shfl_down(cv, o);
        if ((tid & 63) == 0) sredc[tid >> 6] = cv;
        if (tid < 9) {
            float fc = 0.0f;
            for (int w = 0; w < TGT_BLOCKS * 4; w++) fc += st[w * 9 + tid];
            sf[tid] = fc;
        }
        __syncthreads();
        if (tid == 0) {
            float f[9];
            #pragma unroll
            for (int c = 0; c < 9; c++) f[c] = sf[c];
            f[5] += sredc[0] + sredc[1] + sredc[2] + sredc[3];
            float total = f[0] + f[1] + f[2] + f[3] + f[4] + f[6] + f[5];
            out[0] = total;
            out[1] = f[0]; out[2] = f[1]; out[3] = f[2]; out[4] = f[3];
            out[5] = f[4]; out[6] = f[5]; out[7] = f[6];
            float nGT = f[7], nCorr = f[8];
            out[8] = (nGT > 0.0f) ? (nCorr / fmaxf(nGT, 1.0f)) : 1.0f;
        }
        return;
    }

    if (bid <= CONF_BLOCKS) {
        // ---- dense 0.5*sum(sigmoid(conf)^2); 4 blocks/plane, barrier-free ----
        const float4* X4 = reinterpret_cast<const float4*>(X);
        int cb = bid - 1;
        int p = cb >> 2, q = cb & 3;       // plane 0..47, quarter
        int bb = p / 3, aa = p - bb * 3;
        int base4 = (bb * 48 + aa * 16 + 4) * 4096 + q * 1024;
        float s = 0.0f;
        #pragma unroll
        for (int k = 0; k < 4; k++) {
            float4 v = X4[base4 + k * 256 + tid];
            float c0 = sigm(v.x), c1 = sigm(v.y), c2 = sigm(v.z), c3 = sigm(v.w);
            s += c0 * c0 + c1 * c1 + c2 * c2 + c3 * c3;
        }
        #pragma unroll
        for (int o = 32; o > 0; o >>= 1) s += __shfl_down(s, o);
        if ((tid & 63) == 0)
            put_slot(&slots[cb * 4 + (tid >> 6)], 0.5f * s);
        return;
    }

    // ---- target block: one batch, thread = (target t, anchor a), tid = t*3+a ----
    __shared__ int pk[NT];
    __shared__ int sanyv[NT * 3];
    int b = bid - 1 - CONF_BLOCKS;

    TInfo me; me.selm = 0;
    int t = 0, a = 0;
    if (tid < NT * 3) {
        t = tid / 3; a = tid - t * 3;
        const float* tp = T + b * NT * 5 + t * 5;   // read own target directly
        float tg5[5] = {tp[0], tp[1], tp[2], tp[3], tp[4]};
        me = tinfo(tg5);
        if (a == 0) pk[t] = me.gi | (me.gj << 7) | (me.selm << 14) | (me.cls << 17);
    }
    bool selA = (tid < NT * 3) && ((me.selm >> a) & 1);

    // issue all scattered X loads BEFORE the barrier; consumed after the pk scan
    float x0 = 0, x1 = 0, x2 = 0, x3 = 0, cf = 0, l[NC];
    float awa = (a == 0) ? 14.5f  : (a == 1) ? 19.5f  : 46.625f;
    float aha = (a == 0) ? 11.25f : (a == 1) ? 24.75f : 40.75f;
    if (selA) {
        int base = (b * 48 + a * 16) * PLANE + me.gj * GDIM + me.gi;
        x0 = X[base];
        x1 = X[base + PLANE];
        x2 = X[base + 2 * PLANE];
        x3 = X[base + 3 * PLANE];
        cf = X[base + 4 * PLANE];
        #pragma unroll
        for (int c = 0; c < NC; c++) l[c] = X[base + (5 + c) * PLANE];
    }
    __syncthreads();

    float res[9] = {0, 0, 0, 0, 0, 0, 0, 0, 0};
    // res: 0..3 lx,ly,lw,lh  4 lconf  5 lconf_no(corr)  6 lcls  7 nGT  8 nCorrect
    int anyv = 0;
    if (selA) {
        int mykey = me.gi | (me.gj << 7);
        int lat = 0, clsba = 0;
        for (int e = 0; e < NT; e++) {           // overlaps with X loads in flight
            int o = pk[e];
            if (((o >> (14 + a)) & 1) && ((o & 0x3FFF) == mykey)) {
                clsba |= 1 << ((o >> 17) & 0xF);
                if (e > t) lat = 1;
            }
        }
        // nCorrect: center IoU of pred box vs gt at this cell-anchor
        float g_x1 = me.gx - me.gw * 0.5f, g_x2 = me.gx + me.gw * 0.5f;
        float g_y1 = me.gy - me.gh * 0.5f, g_y2 = me.gy + me.gh * 0.5f;
        float bx = sigm(x0) + (float)me.gi;
        float by = sigm(x1) + (float)me.gj;
        float bw = expf(x2) * awa;
        float bh = expf(x3) * aha;
        float iw = fmaxf(fminf(g_x2, bx + bw * 0.5f) - fmaxf(g_x1, bx - bw * 0.5f), 0.0f);
        float ih = fmaxf(fminf(g_y2, by + bh * 0.5f) - fmaxf(g_y1, by - bh * 0.5f), 0.0f);
        float inter = iw * ih;
        float iou = inter / (me.gw * me.gh + bw * bh - inter + 1e-16f);
        anyv = (iou > 0.5f) ? 1 : 0;

        if (!lat) {   // unique last-writer for this cell-anchor
            float conf = sigm(cf);
            float px = sigm(x0), py = sigm(x1);
            float txv = me.gx - (float)me.gi;
            float tyv = me.gy - (float)me.gj;
            float twv = logf(me.gw / awa + 1e-16f);
            float thv = logf(me.gh / aha + 1e-16f);
            res[0] = 100.0f * (px - txv) * (px - txv);
            res[1] = 100.0f * (py - tyv) * (py - tyv);
            res[2] = 100.0f * (x2 - twv) * (x2 - twv);
            res[3] = 100.0f * (x3 - thv) * (x3 - thv);
            res[4] = (conf - 1.0f) * (conf - 1.0f);
            res[5] = -0.5f * conf * conf;   // cancel dense no-obj term
            float mx = -1e30f;
            #pragma unroll
            for (int c = 0; c < NC; c++) mx = fmaxf(mx, l[c]);
            float S = 0.0f;
            #pragma unroll
            for (int c = 0; c < NC; c++) { l[c] = expf(l[c] - mx); S += l[c]; }
            float invS = 1.0f / S;
            float lcls = 0.0f;
            #pragma unroll
            for (int c = 0; c < NC; c++) {
                float p = l[c] * invS;
                float term = ((clsba >> c) & 1) ? fmaxf(logf(p), -100.0f)
                                                : fmaxf(logf(1.0f - p), -100.0f);
                lcls -= term;
            }
            res[6] = lcls;
        }
    }
    if (tid < NT * 3) sanyv[tid] = anyv;
    if (tid < NT * 3 && a == 0 && me.selm) res[7] = 1.0f;   // nGT (valid <=> selm!=0)
    __syncthreads();
    if (tid < NT * 3 && a == 0 && me.selm)
        res[8] = (sanyv[tid] | sanyv[tid + 1] | sanyv[tid + 2]) ? 1.0f : 0.0f;

    #pragma unroll
    for (int o = 32; o > 0; o >>= 1) {
        #pragma unroll
        for (int c = 0; c < 9; c++) res[c] += __shfl_down(res[c], o);
    }
    if ((tid & 63) == 0) {
        int w = tid >> 6;
        #pragma unroll
        for (int c = 0; c < 9; c++)
            put_slot(&slots[NCONF_SLOTS + (b * 4 + w) * 9 + c], res[c]);
    }
}

extern "C" void kernel_launch(void* const* d_in, const int* in_sizes, int n_in,
                              void* d_out, int out_size, void* d_ws, size_t ws_size,
                              hipStream_t stream) {
    const float* X = (const float*)d_in[0];   // (16,48,128,128) f32
    const float* T = (const float*)d_in[1];   // (16,50,5) f32
    float* out = (float*)d_out;               // 9 f32 scalars
    float* wsf = (float*)d_ws;

    k_fused<<<TOTAL_BLOCKS, TPB, 0, stream>>>(X, T, wsf, out);
}